// Round 6
// baseline (287.556 us; speedup 1.0000x reference)
//
#include <hip/hip_runtime.h>
#include <hip/hip_bf16.h>
#include <math.h>

// Problem constants (fixed by reference: b=2, h=w=64, dim=256, attn_dim=128, HEAD=4)
#define N_TOK 4096
#define C_DIM 256
#define A_DIM 128
#define HEADS 4
#define HD    32
#define NBAT  2
#define BH    (NBAT * HEADS)

// (1/sqrt(32)) * log2(e) — folded into Wq at pack time
#define SCALE_LOG2E 0.25503521f

#define SPLITS 8
#define KEYS_PER_SPLIT (N_TOK / SPLITS)

// padded LDS strides for attention (shorts)
#define KS 36
#define VS 72
#define PS 36

typedef __attribute__((ext_vector_type(8))) short short8;   // 8 bf16 frag
typedef __attribute__((ext_vector_type(4))) short short4_t; // 4 bf16
typedef __attribute__((ext_vector_type(4))) float floatx4;  // MFMA C/D frag

__device__ __forceinline__ unsigned short f2bf(float f) {   // RNE
    unsigned int u = __float_as_uint(f);
    u = (u + 0x7fffu + ((u >> 16) & 1u)) >> 16;
    return (unsigned short)u;
}
__device__ __forceinline__ unsigned short f2bf_pos(float f) { // cheap RN (positive vals)
    return (unsigned short)((__float_as_uint(f) + 0x8000u) >> 16);
}
__device__ __forceinline__ float bf2f(unsigned short u) {
    return __uint_as_float((unsigned int)u << 16);
}

// ---------------------------------------------------------------------------
// K0: pack weights fp32 -> bf16 in B-fragment order.
// Layout: Wp[wid][step s][tile t][lane][j]  (wid: 0=Wq(scaled) 1=Wk 2=Wv 3=Wo)
// B-frag semantics: lane=(quad,l15) holds B[k = quad*8+j][n = t*16+l15].
// ---------------------------------------------------------------------------
__global__ __launch_bounds__(256) void wpack_kernel(
    const float* __restrict__ Wq, const float* __restrict__ Wk,
    const float* __restrict__ Wv, const float* __restrict__ Wo,
    unsigned short* __restrict__ Wp)
{
    const int chunk = blockIdx.x * 256 + threadIdx.x;  // [0, 16384): 8 shorts each
    const int wid = chunk >> 12;
    const int c = chunk & 4095;
    const int lane = c & 63, quad = lane >> 4, l15 = lane & 15;
    short8 v;
    if (wid < 3) {
        const int s = c >> 9, t = (c >> 6) & 7;
        const float* W = (wid == 0) ? Wq : ((wid == 1) ? Wk : Wv);
        const float scale = (wid == 0) ? SCALE_LOG2E : 1.0f;
        const int src = (s * 32 + quad * 8) * A_DIM + t * 16 + l15;
        #pragma unroll
        for (int j = 0; j < 8; j++) v[j] = (short)f2bf(W[src + j * A_DIM] * scale);
    } else {
        const int s = c >> 10, t = (c >> 6) & 15;
        const int src = (s * 32 + quad * 8) * C_DIM + t * 16 + l15;
        #pragma unroll
        for (int j = 0; j < 8; j++) v[j] = (short)f2bf(Wo[src + j * C_DIM]);
    }
    *(short8*)(Wp + (long)chunk * 8) = v;
}

// ---------------------------------------------------------------------------
// K1: QKV projection via MFMA. 512 blocks x 4 waves (2 waves/SIMD).
// Block = 16 rows x 128 cols; wave ch = w owns 16 rows x 32 cols x {Q,K,V}
// (6 accumulators). Q,K stored [bh][n][32]; V transposed via LDS.
// ---------------------------------------------------------------------------
__global__ __launch_bounds__(256) void qkv_kernel(
    const float* __restrict__ query, const float* __restrict__ context,
    const unsigned short* __restrict__ Wp,
    unsigned short* __restrict__ Qb, unsigned short* __restrict__ Kb,
    unsigned short* __restrict__ Vb)
{
    __shared__ __align__(16) unsigned short V_lds[128 * 18];  // [col][tok16+pad] 4.5KB

    const int tid = threadIdx.x;
    const int w = tid >> 6, lane = tid & 63;
    const int quad = lane >> 4, l15 = lane & 15;
    const int ch = w;                      // col quarter (32 cols)
    const long i0 = (long)blockIdx.x * 16;
    const long row = i0 + l15;

    const unsigned short* Wqp = Wp;
    const unsigned short* Wkp = Wp + 32768;
    const unsigned short* Wvp = Wp + 65536;

    floatx4 aQ[2] = {}, aK[2] = {}, aV[2] = {};

    for (int s = 0; s < 8; s++) {
        const float* qp = query + row * C_DIM + s * 32 + quad * 8;
        const float* cp = context + row * C_DIM + s * 32 + quad * 8;
        floatx4 q0 = *(const floatx4*)qp, q1 = *(const floatx4*)(qp + 4);
        floatx4 c0 = *(const floatx4*)cp, c1 = *(const floatx4*)(cp + 4);
        short8 aq, ac;
        #pragma unroll
        for (int j = 0; j < 4; j++) {
            aq[j] = (short)f2bf(q0[j]); aq[4 + j] = (short)f2bf(q1[j]);
            ac[j] = (short)f2bf(c0[j]); ac[4 + j] = (short)f2bf(c1[j]);
        }
        #pragma unroll
        for (int tp = 0; tp < 2; tp++) {
            const long fo = ((long)(s * 8 + ch * 2 + tp) * 64 + lane) * 8;
            short8 bq = *(const short8*)(Wqp + fo);
            short8 bk = *(const short8*)(Wkp + fo);
            short8 bv = *(const short8*)(Wvp + fo);
            aQ[tp] = __builtin_amdgcn_mfma_f32_16x16x32_bf16(aq, bq, aQ[tp], 0, 0, 0);
            aK[tp] = __builtin_amdgcn_mfma_f32_16x16x32_bf16(ac, bk, aK[tp], 0, 0, 0);
            aV[tp] = __builtin_amdgcn_mfma_f32_16x16x32_bf16(ac, bv, aV[tp], 0, 0, 0);
        }
    }

    const long b = i0 >> 12;
    const long n0 = i0 & (N_TOK - 1);
    const long nbase = n0 + quad * 4;
    #pragma unroll
    for (int tp = 0; tp < 2; tp++) {
        const int col = ch * 32 + tp * 16 + l15;
        const int h = col >> 5, d = col & 31;
        unsigned short* qdst = Qb + ((b * HEADS + h) * N_TOK + nbase) * HD + d;
        unsigned short* kdst = Kb + ((b * HEADS + h) * N_TOK + nbase) * HD + d;
        #pragma unroll
        for (int r = 0; r < 4; r++) {
            qdst[r * HD] = f2bf(aQ[tp][r]);
            kdst[r * HD] = f2bf(aK[tp][r]);
        }
        short4_t pv;
        #pragma unroll
        for (int r = 0; r < 4; r++) pv[r] = (short)f2bf(aV[tp][r]);
        *(short4_t*)&V_lds[col * 18 + quad * 4] = pv;
    }
    __syncthreads();

    {   // cooperative V^T write-out: 128 cols x 16 tokens; 16B chunks
        const int col = tid >> 1, seg = tid & 1;
        const int h = col >> 5, d = col & 31;
        unsigned short* dst = Vb + ((b * HEADS + h) * HD + d) * N_TOK + n0 + seg * 8;
        *(short8*)dst = *(const short8*)&V_lds[col * 18 + seg * 8];
    }
}

// ---------------------------------------------------------------------------
// K2: flash attention, no-max softmax, split-K=8.
// Grid (32 qblocks, 8 bh, 8 splits) = 2048 blocks -> 8 blocks/CU, 32 waves/CU.
// launch_bounds(256,8): VGPR<=64 (uses 56), LDS 8x18KB=144KB/CU.
// ---------------------------------------------------------------------------
__global__ __launch_bounds__(256, 8) void attn_kernel(
    const unsigned short* __restrict__ Qb, const unsigned short* __restrict__ Kb,
    const unsigned short* __restrict__ Vb,
    unsigned short* __restrict__ AO, float* __restrict__ Lbuf)
{
    __shared__ __align__(16) unsigned short K_lds[64 * KS];        // 4.5 KB
    __shared__ __align__(16) unsigned short V_lds[HD * VS];        // 4.5 KB
    __shared__ __align__(16) unsigned short P_lds[4][2 * 16 * PS]; // 9 KB

    const int tid  = threadIdx.x;
    const int w    = tid >> 6;
    const int lane = tid & 63;
    const int quad = lane >> 4;
    const int l15  = lane & 15;
    const int bh   = blockIdx.y;
    const int z    = blockIdx.z;
    const int i0   = blockIdx.x * 128 + w * 32;

    const unsigned short* Qh = Qb + (long)bh * N_TOK * HD;
    const unsigned short* Kh = Kb + (long)bh * N_TOK * HD;
    const unsigned short* Vh = Vb + (long)bh * HD * N_TOK;

    const short8 qfA = *(const short8*)(Qh + (long)(i0 + l15) * HD + quad * 8);
    const short8 qfB = *(const short8*)(Qh + (long)(i0 + 16 + l15) * HD + quad * 8);

    floatx4 accA0 = {0.f,0.f,0.f,0.f}, accA1 = {0.f,0.f,0.f,0.f};
    floatx4 accB0 = {0.f,0.f,0.f,0.f}, accB1 = {0.f,0.f,0.f,0.f};
    floatx4 lA = {0.f,0.f,0.f,0.f}, lB = {0.f,0.f,0.f,0.f};

    const int  kst = (tid >> 2) * KS + (tid & 3) * 8;
    const int  vst = (tid >> 3) * VS + (tid & 7) * 8;
    const long vgl = (long)(tid >> 3) * N_TOK + (tid & 7) * 8;
    unsigned short* Pw  = P_lds[w];
    unsigned short* PwB = P_lds[w] + 16 * PS;

    const int j_lo = z * KEYS_PER_SPLIT, j_hi = j_lo + KEYS_PER_SPLIT;

    // prefetch tile 0 into registers
    short8 kreg = *(const short8*)(Kh + (long)j_lo * HD + tid * 8);
    short8 vreg = *(const short8*)(Vh + vgl + j_lo);

    for (int j0 = j_lo; j0 < j_hi; j0 += 64) {
        __syncthreads();
        *(short8*)&K_lds[kst] = kreg;
        *(short8*)&V_lds[vst] = vreg;
        if (j0 + 64 < j_hi) {   // prefetch next tile (overlaps with compute)
            kreg = *(const short8*)(Kh + (long)(j0 + 64) * HD + tid * 8);
            vreg = *(const short8*)(Vh + vgl + j0 + 64);
        }
        __syncthreads();

        #pragma unroll
        for (int sub = 0; sub < 2; sub++) {
            const int jb = sub * 32;
            short8 kf0 = *(short8*)&K_lds[(jb + l15) * KS + quad * 8];
            short8 kf1 = *(short8*)&K_lds[(jb + 16 + l15) * KS + quad * 8];
            const floatx4 zf = {0.f,0.f,0.f,0.f};
            floatx4 sA0 = __builtin_amdgcn_mfma_f32_16x16x32_bf16(qfA, kf0, zf, 0, 0, 0);
            floatx4 sA1 = __builtin_amdgcn_mfma_f32_16x16x32_bf16(qfA, kf1, zf, 0, 0, 0);
            floatx4 sB0 = __builtin_amdgcn_mfma_f32_16x16x32_bf16(qfB, kf0, zf, 0, 0, 0);
            floatx4 sB1 = __builtin_amdgcn_mfma_f32_16x16x32_bf16(qfB, kf1, zf, 0, 0, 0);

            floatx4 pA0, pA1, pB0, pB1;
            #pragma unroll
            for (int r = 0; r < 4; r++) {
                pA0[r] = __builtin_amdgcn_exp2f(sA0[r]);
                pA1[r] = __builtin_amdgcn_exp2f(sA1[r]);
                pB0[r] = __builtin_amdgcn_exp2f(sB0[r]);
                pB1[r] = __builtin_amdgcn_exp2f(sB1[r]);
                lA[r] += pA0[r] + pA1[r];
                lB[r] += pB0[r] + pB1[r];
            }

            #pragma unroll
            for (int r = 0; r < 4; r++) {
                const int rw = (quad * 4 + r) * PS;
                Pw[rw + l15]       = f2bf_pos(pA0[r]);
                Pw[rw + 16 + l15]  = f2bf_pos(pA1[r]);
                PwB[rw + l15]      = f2bf_pos(pB0[r]);
                PwB[rw + 16 + l15] = f2bf_pos(pB1[r]);
            }
            short8 pfA = *(short8*)&Pw[l15 * PS + quad * 8];
            short8 pfB = *(short8*)&PwB[l15 * PS + quad * 8];

            short8 vf0 = *(short8*)&V_lds[l15 * VS + jb + quad * 8];
            short8 vf1 = *(short8*)&V_lds[(16 + l15) * VS + jb + quad * 8];
            accA0 = __builtin_amdgcn_mfma_f32_16x16x32_bf16(pfA, vf0, accA0, 0, 0, 0);
            accA1 = __builtin_amdgcn_mfma_f32_16x16x32_bf16(pfA, vf1, accA1, 0, 0, 0);
            accB0 = __builtin_amdgcn_mfma_f32_16x16x32_bf16(pfB, vf0, accB0, 0, 0, 0);
            accB1 = __builtin_amdgcn_mfma_f32_16x16x32_bf16(pfB, vf1, accB1, 0, 0, 0);
        }
    }

    #pragma unroll
    for (int off = 1; off < 16; off <<= 1) {
        #pragma unroll
        for (int r = 0; r < 4; r++) {
            lA[r] += __shfl_xor(lA[r], off);
            lB[r] += __shfl_xor(lB[r], off);
        }
    }

    const int b = bh >> 2, h = bh & 3;
    unsigned short* AOz = AO + (long)z * (NBAT * N_TOK * A_DIM);
    float* Lz = Lbuf + (long)z * (BH * N_TOK);
    #pragma unroll
    for (int r = 0; r < 4; r++) {
        const float invA = 1.0f / lA[r];
        const float invB = 1.0f / lB[r];
        const long rowA = (long)b * N_TOK + i0 + quad * 4 + r;
        const long rowB = rowA + 16;
        AOz[rowA * A_DIM + h * HD + l15]      = f2bf(accA0[r] * invA);
        AOz[rowA * A_DIM + h * HD + 16 + l15] = f2bf(accA1[r] * invA);
        AOz[rowB * A_DIM + h * HD + l15]      = f2bf(accB0[r] * invB);
        AOz[rowB * A_DIM + h * HD + 16 + l15] = f2bf(accB1[r] * invB);
        if (l15 == 0) {
            Lz[(long)bh * N_TOK + i0 + quad * 4 + r]      = lA[r];
            Lz[(long)bh * N_TOK + i0 + 16 + quad * 4 + r] = lB[r];
        }
    }
}

// ---------------------------------------------------------------------------
// K3: split-K combine + out-projection via MFMA. 512 blocks x 4 waves.
// Block = 16 rows x 256 cols; wave ch owns 16 rows x 64 cols.
// ---------------------------------------------------------------------------
__global__ __launch_bounds__(256) void outproj_kernel(
    const unsigned short* __restrict__ AO, const float* __restrict__ Lbuf,
    const unsigned short* __restrict__ Wp, float* __restrict__ out)
{
    const int tid = threadIdx.x;
    const int w = tid >> 6, lane = tid & 63;
    const int quad = lane >> 4, l15 = lane & 15;
    const int ch = w;                       // col quarter (64 cols)
    const long i0 = (long)blockIdx.x * 16;
    const long row = i0 + l15;
    const int b = (int)(row >> 12);
    const int n = (int)(row & (N_TOK - 1));
    const unsigned short* Wop = Wp + 98304;

    floatx4 acc[4] = {};

    #pragma unroll
    for (int s = 0; s < 4; s++) {   // k-step == head s (32-aligned)
        float lz[SPLITS], lsum = 0.f;
        #pragma unroll
        for (int z = 0; z < SPLITS; z++) {
            lz[z] = Lbuf[(long)z * (BH * N_TOK) + (long)(b * HEADS + s) * N_TOK + n];
            lsum += lz[z];
        }
        const float inv = 1.0f / lsum;
        float vals[8] = {};
        #pragma unroll
        for (int z = 0; z < SPLITS; z++) {
            short8 az = *(const short8*)(AO + (long)z * (NBAT * N_TOK * A_DIM) +
                                         row * A_DIM + s * 32 + quad * 8);
            const float wz = lz[z] * inv;
            #pragma unroll
            for (int j = 0; j < 8; j++) vals[j] += wz * bf2f((unsigned short)az[j]);
        }
        short8 af;
        #pragma unroll
        for (int j = 0; j < 8; j++) af[j] = (short)f2bf(vals[j]);
        #pragma unroll
        for (int tp = 0; tp < 4; tp++) {
            const int t = ch * 4 + tp;
            short8 bo = *(const short8*)(Wop + ((long)(s * 16 + t) * 64 + lane) * 8);
            acc[tp] = __builtin_amdgcn_mfma_f32_16x16x32_bf16(af, bo, acc[tp], 0, 0, 0);
        }
    }

    #pragma unroll
    for (int tp = 0; tp < 4; tp++) {
        #pragma unroll
        for (int r = 0; r < 4; r++)
            out[(i0 + quad * 4 + r) * C_DIM + (ch * 4 + tp) * 16 + l15] = acc[tp][r];
    }
}

// ---------------------------------------------------------------------------
extern "C" void kernel_launch(void* const* d_in, const int* in_sizes, int n_in,
                              void* d_out, int out_size, void* d_ws, size_t ws_size,
                              hipStream_t stream)
{
    const float* query   = (const float*)d_in[0];
    const float* context = (const float*)d_in[1];
    const float* Wq      = (const float*)d_in[2];
    const float* Wk      = (const float*)d_in[3];
    const float* Wv      = (const float*)d_in[4];
    const float* Wo      = (const float*)d_in[5];
    float* out = (float*)d_out;

    char* ws = (char*)d_ws;
    unsigned short* Qb = (unsigned short*)(ws);                    // 2 MB [bh][n][32]
    unsigned short* Kb = (unsigned short*)(ws + (2 << 20));        // 2 MB [bh][n][32]
    unsigned short* Vb = (unsigned short*)(ws + (4 << 20));        // 2 MB [bh][32][n]
    unsigned short* AO = (unsigned short*)(ws + (6 << 20));        // 16 MB [8][b*n][128] bf16
    float*          Lb = (float*)(ws + (22 << 20));                // 1 MB [8][bh][n]
    unsigned short* Wp = (unsigned short*)(ws + (23 << 20));       // 256 KB packed

    wpack_kernel<<<dim3(64), dim3(256), 0, stream>>>(Wq, Wk, Wv, Wo, Wp);
    qkv_kernel<<<dim3(512), dim3(256), 0, stream>>>(query, context, Wp, Qb, Kb, Vb);
    attn_kernel<<<dim3(N_TOK / 128, BH, SPLITS), dim3(256), 0, stream>>>(
        Qb, Kb, Vb, AO, Lb);
    outproj_kernel<<<dim3(512), dim3(256), 0, stream>>>(AO, Lb, Wp, out);
}

// Round 7
// 155.605 us; speedup vs baseline: 1.8480x; 1.8480x over previous
//
#include <hip/hip_runtime.h>
#include <hip/hip_bf16.h>
#include <math.h>

// Problem constants (fixed by reference: b=2, h=w=64, dim=256, attn_dim=128, HEAD=4)
#define N_TOK 4096
#define C_DIM 256
#define A_DIM 128
#define HEADS 4
#define HD    32
#define NBAT  2
#define BH    (NBAT * HEADS)

// (1/sqrt(32)) * log2(e) — folded into Wq at pack time
#define SCALE_LOG2E 0.25503521f

#define SPLITS 8
#define KEYS_PER_SPLIT (N_TOK / SPLITS)

// padded LDS strides for attention (shorts)
#define KS 36
#define VS 72
#define PS 36

typedef __attribute__((ext_vector_type(8))) short short8;   // 8 bf16 frag
typedef __attribute__((ext_vector_type(4))) short short4_t; // 4 bf16
typedef __attribute__((ext_vector_type(4))) float floatx4;  // MFMA C/D frag

__device__ __forceinline__ unsigned short f2bf(float f) {   // RNE
    unsigned int u = __float_as_uint(f);
    u = (u + 0x7fffu + ((u >> 16) & 1u)) >> 16;
    return (unsigned short)u;
}
__device__ __forceinline__ unsigned short f2bf_pos(float f) { // cheap RN (positive vals)
    return (unsigned short)((__float_as_uint(f) + 0x8000u) >> 16);
}
__device__ __forceinline__ float bf2f(unsigned short u) {
    return __uint_as_float((unsigned int)u << 16);
}

// ---------------------------------------------------------------------------
// K0: pack weights fp32 -> bf16 in B-fragment order.
// Layout: Wp[wid][step s][tile t][lane][j]  (wid: 0=Wq(scaled) 1=Wk 2=Wv 3=Wo)
// B-frag semantics: lane=(quad,l15) holds B[k = quad*8+j][n = t*16+l15].
// ---------------------------------------------------------------------------
__global__ __launch_bounds__(256) void wpack_kernel(
    const float* __restrict__ Wq, const float* __restrict__ Wk,
    const float* __restrict__ Wv, const float* __restrict__ Wo,
    unsigned short* __restrict__ Wp)
{
    const int chunk = blockIdx.x * 256 + threadIdx.x;  // [0, 16384): 8 shorts each
    const int wid = chunk >> 12;
    const int c = chunk & 4095;
    const int lane = c & 63, quad = lane >> 4, l15 = lane & 15;
    short8 v;
    if (wid < 3) {
        const int s = c >> 9, t = (c >> 6) & 7;
        const float* W = (wid == 0) ? Wq : ((wid == 1) ? Wk : Wv);
        const float scale = (wid == 0) ? SCALE_LOG2E : 1.0f;
        const int src = (s * 32 + quad * 8) * A_DIM + t * 16 + l15;
        #pragma unroll
        for (int j = 0; j < 8; j++) v[j] = (short)f2bf(W[src + j * A_DIM] * scale);
    } else {
        const int s = c >> 10, t = (c >> 6) & 15;
        const int src = (s * 32 + quad * 8) * C_DIM + t * 16 + l15;
        #pragma unroll
        for (int j = 0; j < 8; j++) v[j] = (short)f2bf(Wo[src + j * C_DIM]);
    }
    *(short8*)(Wp + (long)chunk * 8) = v;
}

// ---------------------------------------------------------------------------
// K1: QKV projection via MFMA. 512 blocks x 4 waves (2 waves/SIMD).
// Block = 16 rows x 128 cols; wave ch = w owns 16 rows x 32 cols x {Q,K,V}
// (6 accumulators). Q,K stored [bh][n][32]; V transposed via LDS.
// ---------------------------------------------------------------------------
__global__ __launch_bounds__(256) void qkv_kernel(
    const float* __restrict__ query, const float* __restrict__ context,
    const unsigned short* __restrict__ Wp,
    unsigned short* __restrict__ Qb, unsigned short* __restrict__ Kb,
    unsigned short* __restrict__ Vb)
{
    __shared__ __align__(16) unsigned short V_lds[128 * 18];  // [col][tok16+pad] 4.5KB

    const int tid = threadIdx.x;
    const int w = tid >> 6, lane = tid & 63;
    const int quad = lane >> 4, l15 = lane & 15;
    const int ch = w;                      // col quarter (32 cols)
    const long i0 = (long)blockIdx.x * 16;
    const long row = i0 + l15;

    const unsigned short* Wqp = Wp;
    const unsigned short* Wkp = Wp + 32768;
    const unsigned short* Wvp = Wp + 65536;

    floatx4 aQ[2] = {}, aK[2] = {}, aV[2] = {};

    for (int s = 0; s < 8; s++) {
        const float* qp = query + row * C_DIM + s * 32 + quad * 8;
        const float* cp = context + row * C_DIM + s * 32 + quad * 8;
        floatx4 q0 = *(const floatx4*)qp, q1 = *(const floatx4*)(qp + 4);
        floatx4 c0 = *(const floatx4*)cp, c1 = *(const floatx4*)(cp + 4);
        short8 aq, ac;
        #pragma unroll
        for (int j = 0; j < 4; j++) {
            aq[j] = (short)f2bf(q0[j]); aq[4 + j] = (short)f2bf(q1[j]);
            ac[j] = (short)f2bf(c0[j]); ac[4 + j] = (short)f2bf(c1[j]);
        }
        #pragma unroll
        for (int tp = 0; tp < 2; tp++) {
            const long fo = ((long)(s * 8 + ch * 2 + tp) * 64 + lane) * 8;
            short8 bq = *(const short8*)(Wqp + fo);
            short8 bk = *(const short8*)(Wkp + fo);
            short8 bv = *(const short8*)(Wvp + fo);
            aQ[tp] = __builtin_amdgcn_mfma_f32_16x16x32_bf16(aq, bq, aQ[tp], 0, 0, 0);
            aK[tp] = __builtin_amdgcn_mfma_f32_16x16x32_bf16(ac, bk, aK[tp], 0, 0, 0);
            aV[tp] = __builtin_amdgcn_mfma_f32_16x16x32_bf16(ac, bv, aV[tp], 0, 0, 0);
        }
    }

    const long b = i0 >> 12;
    const long n0 = i0 & (N_TOK - 1);
    const long nbase = n0 + quad * 4;
    #pragma unroll
    for (int tp = 0; tp < 2; tp++) {
        const int col = ch * 32 + tp * 16 + l15;
        const int h = col >> 5, d = col & 31;
        unsigned short* qdst = Qb + ((b * HEADS + h) * N_TOK + nbase) * HD + d;
        unsigned short* kdst = Kb + ((b * HEADS + h) * N_TOK + nbase) * HD + d;
        #pragma unroll
        for (int r = 0; r < 4; r++) {
            qdst[r * HD] = f2bf(aQ[tp][r]);
            kdst[r * HD] = f2bf(aK[tp][r]);
        }
        short4_t pv;
        #pragma unroll
        for (int r = 0; r < 4; r++) pv[r] = (short)f2bf(aV[tp][r]);
        *(short4_t*)&V_lds[col * 18 + quad * 4] = pv;
    }
    __syncthreads();

    {   // cooperative V^T write-out: 128 cols x 16 tokens; 16B chunks
        const int col = tid >> 1, seg = tid & 1;
        const int h = col >> 5, d = col & 31;
        unsigned short* dst = Vb + ((b * HEADS + h) * HD + d) * N_TOK + n0 + seg * 8;
        *(short8*)dst = *(const short8*)&V_lds[col * 18 + seg * 8];
    }
}

// ---------------------------------------------------------------------------
// K2: flash attention, no-max softmax, split-K=8.
// Grid (32 qblocks, 8 bh, 8 splits) = 2048 blocks.
// __launch_bounds__(256,4): VGPR cap 128 (kernel uses ~56, NO spills —
// round 6's (256,8) capped at 64 and spilled 900MB to scratch). HW occupancy
// still reaches 8 blocks/CU: VGPR 56 -> 9 waves/SIMD, LDS 18KB -> 8 blocks.
// ---------------------------------------------------------------------------
__global__ __launch_bounds__(256, 4) void attn_kernel(
    const unsigned short* __restrict__ Qb, const unsigned short* __restrict__ Kb,
    const unsigned short* __restrict__ Vb,
    unsigned short* __restrict__ AO, float* __restrict__ Lbuf)
{
    __shared__ __align__(16) unsigned short K_lds[64 * KS];        // 4.5 KB
    __shared__ __align__(16) unsigned short V_lds[HD * VS];        // 4.5 KB
    __shared__ __align__(16) unsigned short P_lds[4][2 * 16 * PS]; // 9 KB

    const int tid  = threadIdx.x;
    const int w    = tid >> 6;
    const int lane = tid & 63;
    const int quad = lane >> 4;
    const int l15  = lane & 15;
    const int bh   = blockIdx.y;
    const int z    = blockIdx.z;
    const int i0   = blockIdx.x * 128 + w * 32;

    const unsigned short* Qh = Qb + (long)bh * N_TOK * HD;
    const unsigned short* Kh = Kb + (long)bh * N_TOK * HD;
    const unsigned short* Vh = Vb + (long)bh * HD * N_TOK;

    const short8 qfA = *(const short8*)(Qh + (long)(i0 + l15) * HD + quad * 8);
    const short8 qfB = *(const short8*)(Qh + (long)(i0 + 16 + l15) * HD + quad * 8);

    floatx4 accA0 = {0.f,0.f,0.f,0.f}, accA1 = {0.f,0.f,0.f,0.f};
    floatx4 accB0 = {0.f,0.f,0.f,0.f}, accB1 = {0.f,0.f,0.f,0.f};
    floatx4 lA = {0.f,0.f,0.f,0.f}, lB = {0.f,0.f,0.f,0.f};

    const int  kst = (tid >> 2) * KS + (tid & 3) * 8;
    const int  vst = (tid >> 3) * VS + (tid & 7) * 8;
    const long vgl = (long)(tid >> 3) * N_TOK + (tid & 7) * 8;
    unsigned short* Pw  = P_lds[w];
    unsigned short* PwB = P_lds[w] + 16 * PS;

    const int j_lo = z * KEYS_PER_SPLIT, j_hi = j_lo + KEYS_PER_SPLIT;

    // prefetch tile 0 into registers
    short8 kreg = *(const short8*)(Kh + (long)j_lo * HD + tid * 8);
    short8 vreg = *(const short8*)(Vh + vgl + j_lo);

    for (int j0 = j_lo; j0 < j_hi; j0 += 64) {
        __syncthreads();
        *(short8*)&K_lds[kst] = kreg;
        *(short8*)&V_lds[vst] = vreg;
        if (j0 + 64 < j_hi) {   // prefetch next tile (overlaps with compute)
            kreg = *(const short8*)(Kh + (long)(j0 + 64) * HD + tid * 8);
            vreg = *(const short8*)(Vh + vgl + j0 + 64);
        }
        __syncthreads();

        #pragma unroll
        for (int sub = 0; sub < 2; sub++) {
            const int jb = sub * 32;
            short8 kf0 = *(short8*)&K_lds[(jb + l15) * KS + quad * 8];
            short8 kf1 = *(short8*)&K_lds[(jb + 16 + l15) * KS + quad * 8];
            const floatx4 zf = {0.f,0.f,0.f,0.f};
            floatx4 sA0 = __builtin_amdgcn_mfma_f32_16x16x32_bf16(qfA, kf0, zf, 0, 0, 0);
            floatx4 sA1 = __builtin_amdgcn_mfma_f32_16x16x32_bf16(qfA, kf1, zf, 0, 0, 0);
            floatx4 sB0 = __builtin_amdgcn_mfma_f32_16x16x32_bf16(qfB, kf0, zf, 0, 0, 0);
            floatx4 sB1 = __builtin_amdgcn_mfma_f32_16x16x32_bf16(qfB, kf1, zf, 0, 0, 0);

            floatx4 pA0, pA1, pB0, pB1;
            #pragma unroll
            for (int r = 0; r < 4; r++) {
                pA0[r] = __builtin_amdgcn_exp2f(sA0[r]);
                pA1[r] = __builtin_amdgcn_exp2f(sA1[r]);
                pB0[r] = __builtin_amdgcn_exp2f(sB0[r]);
                pB1[r] = __builtin_amdgcn_exp2f(sB1[r]);
                lA[r] += pA0[r] + pA1[r];
                lB[r] += pB0[r] + pB1[r];
            }

            #pragma unroll
            for (int r = 0; r < 4; r++) {
                const int rw = (quad * 4 + r) * PS;
                Pw[rw + l15]       = f2bf_pos(pA0[r]);
                Pw[rw + 16 + l15]  = f2bf_pos(pA1[r]);
                PwB[rw + l15]      = f2bf_pos(pB0[r]);
                PwB[rw + 16 + l15] = f2bf_pos(pB1[r]);
            }
            short8 pfA = *(short8*)&Pw[l15 * PS + quad * 8];
            short8 pfB = *(short8*)&PwB[l15 * PS + quad * 8];

            short8 vf0 = *(short8*)&V_lds[l15 * VS + jb + quad * 8];
            short8 vf1 = *(short8*)&V_lds[(16 + l15) * VS + jb + quad * 8];
            accA0 = __builtin_amdgcn_mfma_f32_16x16x32_bf16(pfA, vf0, accA0, 0, 0, 0);
            accA1 = __builtin_amdgcn_mfma_f32_16x16x32_bf16(pfA, vf1, accA1, 0, 0, 0);
            accB0 = __builtin_amdgcn_mfma_f32_16x16x32_bf16(pfB, vf0, accB0, 0, 0, 0);
            accB1 = __builtin_amdgcn_mfma_f32_16x16x32_bf16(pfB, vf1, accB1, 0, 0, 0);
        }
    }

    #pragma unroll
    for (int off = 1; off < 16; off <<= 1) {
        #pragma unroll
        for (int r = 0; r < 4; r++) {
            lA[r] += __shfl_xor(lA[r], off);
            lB[r] += __shfl_xor(lB[r], off);
        }
    }

    const int b = bh >> 2, h = bh & 3;
    unsigned short* AOz = AO + (long)z * (NBAT * N_TOK * A_DIM);
    float* Lz = Lbuf + (long)z * (BH * N_TOK);
    #pragma unroll
    for (int r = 0; r < 4; r++) {
        const float invA = 1.0f / lA[r];
        const float invB = 1.0f / lB[r];
        const long rowA = (long)b * N_TOK + i0 + quad * 4 + r;
        const long rowB = rowA + 16;
        AOz[rowA * A_DIM + h * HD + l15]      = f2bf(accA0[r] * invA);
        AOz[rowA * A_DIM + h * HD + 16 + l15] = f2bf(accA1[r] * invA);
        AOz[rowB * A_DIM + h * HD + l15]      = f2bf(accB0[r] * invB);
        AOz[rowB * A_DIM + h * HD + 16 + l15] = f2bf(accB1[r] * invB);
        if (l15 == 0) {
            Lz[(long)bh * N_TOK + i0 + quad * 4 + r]      = lA[r];
            Lz[(long)bh * N_TOK + i0 + 16 + quad * 4 + r] = lB[r];
        }
    }
}

// ---------------------------------------------------------------------------
// K3: split-K combine + out-projection via MFMA. 512 blocks x 4 waves.
// Block = 16 rows x 256 cols; wave ch owns 16 rows x 64 cols.
// ---------------------------------------------------------------------------
__global__ __launch_bounds__(256) void outproj_kernel(
    const unsigned short* __restrict__ AO, const float* __restrict__ Lbuf,
    const unsigned short* __restrict__ Wp, float* __restrict__ out)
{
    const int tid = threadIdx.x;
    const int w = tid >> 6, lane = tid & 63;
    const int quad = lane >> 4, l15 = lane & 15;
    const int ch = w;                       // col quarter (64 cols)
    const long i0 = (long)blockIdx.x * 16;
    const long row = i0 + l15;
    const int b = (int)(row >> 12);
    const int n = (int)(row & (N_TOK - 1));
    const unsigned short* Wop = Wp + 98304;

    floatx4 acc[4] = {};

    #pragma unroll
    for (int s = 0; s < 4; s++) {   // k-step == head s (32-aligned)
        float lz[SPLITS], lsum = 0.f;
        #pragma unroll
        for (int z = 0; z < SPLITS; z++) {
            lz[z] = Lbuf[(long)z * (BH * N_TOK) + (long)(b * HEADS + s) * N_TOK + n];
            lsum += lz[z];
        }
        const float inv = 1.0f / lsum;
        float vals[8] = {};
        #pragma unroll
        for (int z = 0; z < SPLITS; z++) {
            short8 az = *(const short8*)(AO + (long)z * (NBAT * N_TOK * A_DIM) +
                                         row * A_DIM + s * 32 + quad * 8);
            const float wz = lz[z] * inv;
            #pragma unroll
            for (int j = 0; j < 8; j++) vals[j] += wz * bf2f((unsigned short)az[j]);
        }
        short8 af;
        #pragma unroll
        for (int j = 0; j < 8; j++) af[j] = (short)f2bf(vals[j]);
        #pragma unroll
        for (int tp = 0; tp < 4; tp++) {
            const int t = ch * 4 + tp;
            short8 bo = *(const short8*)(Wop + ((long)(s * 16 + t) * 64 + lane) * 8);
            acc[tp] = __builtin_amdgcn_mfma_f32_16x16x32_bf16(af, bo, acc[tp], 0, 0, 0);
        }
    }

    #pragma unroll
    for (int tp = 0; tp < 4; tp++) {
        #pragma unroll
        for (int r = 0; r < 4; r++)
            out[(i0 + quad * 4 + r) * C_DIM + (ch * 4 + tp) * 16 + l15] = acc[tp][r];
    }
}

// ---------------------------------------------------------------------------
extern "C" void kernel_launch(void* const* d_in, const int* in_sizes, int n_in,
                              void* d_out, int out_size, void* d_ws, size_t ws_size,
                              hipStream_t stream)
{
    const float* query   = (const float*)d_in[0];
    const float* context = (const float*)d_in[1];
    const float* Wq      = (const float*)d_in[2];
    const float* Wk      = (const float*)d_in[3];
    const float* Wv      = (const float*)d_in[4];
    const float* Wo      = (const float*)d_in[5];
    float* out = (float*)d_out;

    char* ws = (char*)d_ws;
    unsigned short* Qb = (unsigned short*)(ws);                    // 2 MB [bh][n][32]
    unsigned short* Kb = (unsigned short*)(ws + (2 << 20));        // 2 MB [bh][n][32]
    unsigned short* Vb = (unsigned short*)(ws + (4 << 20));        // 2 MB [bh][32][n]
    unsigned short* AO = (unsigned short*)(ws + (6 << 20));        // 16 MB [8][b*n][128] bf16
    float*          Lb = (float*)(ws + (22 << 20));                // 1 MB [8][bh][n]
    unsigned short* Wp = (unsigned short*)(ws + (23 << 20));       // 256 KB packed

    wpack_kernel<<<dim3(64), dim3(256), 0, stream>>>(Wq, Wk, Wv, Wo, Wp);
    qkv_kernel<<<dim3(512), dim3(256), 0, stream>>>(query, context, Wp, Qb, Kb, Vb);
    attn_kernel<<<dim3(N_TOK / 128, BH, SPLITS), dim3(256), 0, stream>>>(
        Qb, Kb, Vb, AO, Lb);
    outproj_kernel<<<dim3(512), dim3(256), 0, stream>>>(AO, Lb, Wp, out);
}

// Round 8
// 125.655 us; speedup vs baseline: 2.2885x; 1.2384x over previous
//
#include <hip/hip_runtime.h>
#include <hip/hip_bf16.h>
#include <math.h>

// Problem constants (fixed by reference: b=2, h=w=64, dim=256, attn_dim=128, HEAD=4)
#define N_TOK 4096
#define C_DIM 256
#define A_DIM 128
#define HEADS 4
#define HD    32
#define NBAT  2
#define BH    (NBAT * HEADS)

// (1/sqrt(32)) * log2(e) — folded into Wq at pack time
#define SCALE_LOG2E 0.25503521f

#define SPLITS 8
#define KEYS_PER_SPLIT (N_TOK / SPLITS)

// padded LDS strides for attention (shorts). 40 shorts = 80 B rows: row bases
// are 16B-aligned (true ds_read_b128) and start-bank spread is even (8/bank).
#define KS 40
#define VS 72
#define PS 40

typedef __attribute__((ext_vector_type(8))) short short8;   // 8 bf16 frag
typedef __attribute__((ext_vector_type(4))) short short4_t; // 4 bf16
typedef __attribute__((ext_vector_type(4))) float floatx4;  // MFMA C/D frag

__device__ __forceinline__ unsigned short f2bf(float f) {   // RNE
    unsigned int u = __float_as_uint(f);
    u = (u + 0x7fffu + ((u >> 16) & 1u)) >> 16;
    return (unsigned short)u;
}
__device__ __forceinline__ float bf2f(unsigned short u) {
    return __uint_as_float((unsigned int)u << 16);
}
// pack two positive floats to bf16x2 (round-half-up), lo = a, hi = b
__device__ __forceinline__ unsigned int pack2(float a, float b) {
    unsigned int lo = (__float_as_uint(a) + 0x8000u) >> 16;
    unsigned int hi = (__float_as_uint(b) + 0x8000u) & 0xffff0000u;
    return hi | lo;
}

// ---------------------------------------------------------------------------
// K0: pack weights fp32 -> bf16 in B-fragment order.
// Layout: Wp[wid][step s][tile t][lane][j]  (wid: 0=Wq(scaled) 1=Wk 2=Wv 3=Wo)
// ---------------------------------------------------------------------------
__global__ __launch_bounds__(256) void wpack_kernel(
    const float* __restrict__ Wq, const float* __restrict__ Wk,
    const float* __restrict__ Wv, const float* __restrict__ Wo,
    unsigned short* __restrict__ Wp)
{
    const int chunk = blockIdx.x * 256 + threadIdx.x;  // [0, 16384): 8 shorts each
    const int wid = chunk >> 12;
    const int c = chunk & 4095;
    const int lane = c & 63, quad = lane >> 4, l15 = lane & 15;
    short8 v;
    if (wid < 3) {
        const int s = c >> 9, t = (c >> 6) & 7;
        const float* W = (wid == 0) ? Wq : ((wid == 1) ? Wk : Wv);
        const float scale = (wid == 0) ? SCALE_LOG2E : 1.0f;
        const int src = (s * 32 + quad * 8) * A_DIM + t * 16 + l15;
        #pragma unroll
        for (int j = 0; j < 8; j++) v[j] = (short)f2bf(W[src + j * A_DIM] * scale);
    } else {
        const int s = c >> 10, t = (c >> 6) & 15;
        const int src = (s * 32 + quad * 8) * C_DIM + t * 16 + l15;
        #pragma unroll
        for (int j = 0; j < 8; j++) v[j] = (short)f2bf(Wo[src + j * C_DIM]);
    }
    *(short8*)(Wp + (long)chunk * 8) = v;
}

// ---------------------------------------------------------------------------
// K1: QKV projection via MFMA. 512 blocks x 4 waves (unchanged from round 7).
// ---------------------------------------------------------------------------
__global__ __launch_bounds__(256) void qkv_kernel(
    const float* __restrict__ query, const float* __restrict__ context,
    const unsigned short* __restrict__ Wp,
    unsigned short* __restrict__ Qb, unsigned short* __restrict__ Kb,
    unsigned short* __restrict__ Vb)
{
    __shared__ __align__(16) unsigned short V_lds[128 * 18];  // [col][tok16+pad] 4.5KB

    const int tid = threadIdx.x;
    const int w = tid >> 6, lane = tid & 63;
    const int quad = lane >> 4, l15 = lane & 15;
    const int ch = w;                      // col quarter (32 cols)
    const long i0 = (long)blockIdx.x * 16;
    const long row = i0 + l15;

    const unsigned short* Wqp = Wp;
    const unsigned short* Wkp = Wp + 32768;
    const unsigned short* Wvp = Wp + 65536;

    floatx4 aQ[2] = {}, aK[2] = {}, aV[2] = {};

    for (int s = 0; s < 8; s++) {
        const float* qp = query + row * C_DIM + s * 32 + quad * 8;
        const float* cp = context + row * C_DIM + s * 32 + quad * 8;
        floatx4 q0 = *(const floatx4*)qp, q1 = *(const floatx4*)(qp + 4);
        floatx4 c0 = *(const floatx4*)cp, c1 = *(const floatx4*)(cp + 4);
        short8 aq, ac;
        #pragma unroll
        for (int j = 0; j < 4; j++) {
            aq[j] = (short)f2bf(q0[j]); aq[4 + j] = (short)f2bf(q1[j]);
            ac[j] = (short)f2bf(c0[j]); ac[4 + j] = (short)f2bf(c1[j]);
        }
        #pragma unroll
        for (int tp = 0; tp < 2; tp++) {
            const long fo = ((long)(s * 8 + ch * 2 + tp) * 64 + lane) * 8;
            short8 bq = *(const short8*)(Wqp + fo);
            short8 bk = *(const short8*)(Wkp + fo);
            short8 bv = *(const short8*)(Wvp + fo);
            aQ[tp] = __builtin_amdgcn_mfma_f32_16x16x32_bf16(aq, bq, aQ[tp], 0, 0, 0);
            aK[tp] = __builtin_amdgcn_mfma_f32_16x16x32_bf16(ac, bk, aK[tp], 0, 0, 0);
            aV[tp] = __builtin_amdgcn_mfma_f32_16x16x32_bf16(ac, bv, aV[tp], 0, 0, 0);
        }
    }

    const long b = i0 >> 12;
    const long n0 = i0 & (N_TOK - 1);
    const long nbase = n0 + quad * 4;
    #pragma unroll
    for (int tp = 0; tp < 2; tp++) {
        const int col = ch * 32 + tp * 16 + l15;
        const int h = col >> 5, d = col & 31;
        unsigned short* qdst = Qb + ((b * HEADS + h) * N_TOK + nbase) * HD + d;
        unsigned short* kdst = Kb + ((b * HEADS + h) * N_TOK + nbase) * HD + d;
        #pragma unroll
        for (int r = 0; r < 4; r++) {
            qdst[r * HD] = f2bf(aQ[tp][r]);
            kdst[r * HD] = f2bf(aK[tp][r]);
        }
        short4_t pv;
        #pragma unroll
        for (int r = 0; r < 4; r++) pv[r] = (short)f2bf(aV[tp][r]);
        *(short4_t*)&V_lds[col * 18 + quad * 4] = pv;
    }
    __syncthreads();

    {   // cooperative V^T write-out: 128 cols x 16 tokens; 16B chunks
        const int col = tid >> 1, seg = tid & 1;
        const int h = col >> 5, d = col & 31;
        unsigned short* dst = Vb + ((b * HEADS + h) * HD + d) * N_TOK + n0 + seg * 8;
        *(short8*)dst = *(const short8*)&V_lds[col * 18 + seg * 8];
    }
}

// ---------------------------------------------------------------------------
// K2: flash attention, no-max softmax, split-K=8, S^T formulation.
// QK MFMA operands SWAPPED: mfma(kf, qf) -> S^T in C-layout (rows = keys).
// Lanes then hold 4 consecutive keys per frag -> P packed as bf16x2 and
// written with 8 ds_write_b32 per sub (was 16 ds_write_b16), stored in
// [query][key] rows (stride PS=40, 16B-aligned) -> single b128 A-frag read.
// Per-sub P buffers make sub0/sub1 chains independent.
// Denominator: per-lane column sums, quad-reduced at the end.
// 1D grid 2048 with XCD swizzle: each XCD sees one bh (K/V slice ~512KB).
// ---------------------------------------------------------------------------
__global__ __launch_bounds__(256, 4) void attn_kernel(
    const unsigned short* __restrict__ Qb, const unsigned short* __restrict__ Kb,
    const unsigned short* __restrict__ Vb,
    unsigned short* __restrict__ AO, float* __restrict__ Lbuf)
{
    __shared__ __align__(16) unsigned short K_lds[64 * KS];      // 5 KB
    __shared__ __align__(16) unsigned short V_lds[HD * VS];      // 4.5 KB
    __shared__ __align__(16) unsigned short P_lds[4][2][2 * 16 * PS]; // 20 KB

    const int tid  = threadIdx.x;
    const int w    = tid >> 6;
    const int lane = tid & 63;
    const int quad = lane >> 4;
    const int l15  = lane & 15;

    // XCD swizzle: blocks with equal (bh,z) share L%8 -> same XCD L2.
    const int L  = blockIdx.x;
    const int g  = (L & 7) + 8 * ((L >> 3) >> 5);  // group 0..63
    const int qb = (L >> 3) & 31;                  // q-block 0..31
    const int bh = g & 7;
    const int z  = g >> 3;
    const int i0 = qb * 128 + w * 32;

    const unsigned short* Qh = Qb + (long)bh * N_TOK * HD;
    const unsigned short* Kh = Kb + (long)bh * N_TOK * HD;
    const unsigned short* Vh = Vb + (long)bh * HD * N_TOK;

    const short8 qfA = *(const short8*)(Qh + (long)(i0 + l15) * HD + quad * 8);
    const short8 qfB = *(const short8*)(Qh + (long)(i0 + 16 + l15) * HD + quad * 8);

    floatx4 accA0 = {0.f,0.f,0.f,0.f}, accA1 = {0.f,0.f,0.f,0.f};
    floatx4 accB0 = {0.f,0.f,0.f,0.f}, accB1 = {0.f,0.f,0.f,0.f};
    float lAc = 0.f, lBc = 0.f;   // denom partial for query l15 (this lane's col)

    const int  kst = (tid >> 2) * KS + (tid & 3) * 8;
    const int  vst = (tid >> 3) * VS + (tid & 7) * 8;
    const long vgl = (long)(tid >> 3) * N_TOK + (tid & 7) * 8;
    const int  pwb = l15 * (PS / 2);               // u32 row base for P writes

    const int j_lo = z * KEYS_PER_SPLIT, j_hi = j_lo + KEYS_PER_SPLIT;

    // prefetch tile 0 into registers
    short8 kreg = *(const short8*)(Kh + (long)j_lo * HD + tid * 8);
    short8 vreg = *(const short8*)(Vh + vgl + j_lo);

    for (int j0 = j_lo; j0 < j_hi; j0 += 64) {
        __syncthreads();
        *(short8*)&K_lds[kst] = kreg;
        *(short8*)&V_lds[vst] = vreg;
        if (j0 + 64 < j_hi) {   // prefetch next tile (overlaps with compute)
            kreg = *(const short8*)(Kh + (long)(j0 + 64) * HD + tid * 8);
            vreg = *(const short8*)(Vh + vgl + j0 + 64);
        }
        __syncthreads();

        #pragma unroll
        for (int sub = 0; sub < 2; sub++) {
            const int jb = sub * 32;
            short8 kf0 = *(short8*)&K_lds[(jb + l15) * KS + quad * 8];
            short8 kf1 = *(short8*)&K_lds[(jb + 16 + l15) * KS + quad * 8];
            const floatx4 zf = {0.f,0.f,0.f,0.f};
            // S^T = K · Q^T : C rows = keys, cols = queries
            floatx4 sA0 = __builtin_amdgcn_mfma_f32_16x16x32_bf16(kf0, qfA, zf, 0, 0, 0);
            floatx4 sA1 = __builtin_amdgcn_mfma_f32_16x16x32_bf16(kf1, qfA, zf, 0, 0, 0);
            floatx4 sB0 = __builtin_amdgcn_mfma_f32_16x16x32_bf16(kf0, qfB, zf, 0, 0, 0);
            floatx4 sB1 = __builtin_amdgcn_mfma_f32_16x16x32_bf16(kf1, qfB, zf, 0, 0, 0);

            floatx4 pA0, pA1, pB0, pB1;
            #pragma unroll
            for (int r = 0; r < 4; r++) {
                pA0[r] = __builtin_amdgcn_exp2f(sA0[r]);
                pA1[r] = __builtin_amdgcn_exp2f(sA1[r]);
                pB0[r] = __builtin_amdgcn_exp2f(sB0[r]);
                pB1[r] = __builtin_amdgcn_exp2f(sB1[r]);
                lAc += pA0[r] + pA1[r];
                lBc += pB0[r] + pB1[r];
            }

            // pack pairs of consecutive keys -> 8 ds_write_b32 into [q][k] rows
            unsigned int* Pq = (unsigned int*)&P_lds[w][sub][0];
            Pq[pwb + quad * 2 + 0]       = pack2(pA0[0], pA0[1]);
            Pq[pwb + quad * 2 + 1]       = pack2(pA0[2], pA0[3]);
            Pq[pwb + 8 + quad * 2 + 0]   = pack2(pA1[0], pA1[1]);
            Pq[pwb + 8 + quad * 2 + 1]   = pack2(pA1[2], pA1[3]);
            Pq[320 + pwb + quad * 2 + 0] = pack2(pB0[0], pB0[1]);
            Pq[320 + pwb + quad * 2 + 1] = pack2(pB0[2], pB0[3]);
            Pq[320 + pwb + 8 + quad * 2 + 0] = pack2(pB1[0], pB1[1]);
            Pq[320 + pwb + 8 + quad * 2 + 1] = pack2(pB1[2], pB1[3]);

            short8 pfA = *(short8*)&P_lds[w][sub][l15 * PS + quad * 8];
            short8 pfB = *(short8*)&P_lds[w][sub][16 * PS + l15 * PS + quad * 8];

            short8 vf0 = *(short8*)&V_lds[l15 * VS + jb + quad * 8];
            short8 vf1 = *(short8*)&V_lds[(16 + l15) * VS + jb + quad * 8];
            accA0 = __builtin_amdgcn_mfma_f32_16x16x32_bf16(pfA, vf0, accA0, 0, 0, 0);
            accA1 = __builtin_amdgcn_mfma_f32_16x16x32_bf16(pfA, vf1, accA1, 0, 0, 0);
            accB0 = __builtin_amdgcn_mfma_f32_16x16x32_bf16(pfB, vf0, accB0, 0, 0, 0);
            accB1 = __builtin_amdgcn_mfma_f32_16x16x32_bf16(pfB, vf1, accB1, 0, 0, 0);
        }
    }

    // denom: sum the 4 quads holding the same query column
    lAc += __shfl_xor(lAc, 16); lAc += __shfl_xor(lAc, 32);
    lBc += __shfl_xor(lBc, 16); lBc += __shfl_xor(lBc, 32);

    const int b = bh >> 2, h = bh & 3;
    unsigned short* AOz = AO + (long)z * (NBAT * N_TOK * A_DIM);
    float* Lz = Lbuf + (long)z * (BH * N_TOK);
    if (quad == 0) {   // one lane per query writes the denominator
        Lz[(long)bh * N_TOK + i0 + l15]      = lAc;
        Lz[(long)bh * N_TOK + i0 + 16 + l15] = lBc;
    }
    #pragma unroll
    for (int r = 0; r < 4; r++) {
        // O C-frags: rows = queries quad*4+r; fetch that query's denom by shfl
        const float invA = 1.0f / __shfl(lAc, quad * 4 + r);
        const float invB = 1.0f / __shfl(lBc, quad * 4 + r);
        const long rowA = (long)b * N_TOK + i0 + quad * 4 + r;
        const long rowB = rowA + 16;
        AOz[rowA * A_DIM + h * HD + l15]      = f2bf(accA0[r] * invA);
        AOz[rowA * A_DIM + h * HD + 16 + l15] = f2bf(accA1[r] * invA);
        AOz[rowB * A_DIM + h * HD + l15]      = f2bf(accB0[r] * invB);
        AOz[rowB * A_DIM + h * HD + 16 + l15] = f2bf(accB1[r] * invB);
    }
}

// ---------------------------------------------------------------------------
// K3: split-K combine + out-projection via MFMA. 512 blocks x 4 waves
// (unchanged from round 7).
// ---------------------------------------------------------------------------
__global__ __launch_bounds__(256) void outproj_kernel(
    const unsigned short* __restrict__ AO, const float* __restrict__ Lbuf,
    const unsigned short* __restrict__ Wp, float* __restrict__ out)
{
    const int tid = threadIdx.x;
    const int w = tid >> 6, lane = tid & 63;
    const int quad = lane >> 4, l15 = lane & 15;
    const int ch = w;                       // col quarter (64 cols)
    const long i0 = (long)blockIdx.x * 16;
    const long row = i0 + l15;
    const int b = (int)(row >> 12);
    const int n = (int)(row & (N_TOK - 1));
    const unsigned short* Wop = Wp + 98304;

    floatx4 acc[4] = {};

    #pragma unroll
    for (int s = 0; s < 4; s++) {   // k-step == head s (32-aligned)
        float lz[SPLITS], lsum = 0.f;
        #pragma unroll
        for (int z = 0; z < SPLITS; z++) {
            lz[z] = Lbuf[(long)z * (BH * N_TOK) + (long)(b * HEADS + s) * N_TOK + n];
            lsum += lz[z];
        }
        const float inv = 1.0f / lsum;
        float vals[8] = {};
        #pragma unroll
        for (int z = 0; z < SPLITS; z++) {
            short8 az = *(const short8*)(AO + (long)z * (NBAT * N_TOK * A_DIM) +
                                         row * A_DIM + s * 32 + quad * 8);
            const float wz = lz[z] * inv;
            #pragma unroll
            for (int j = 0; j < 8; j++) vals[j] += wz * bf2f((unsigned short)az[j]);
        }
        short8 af;
        #pragma unroll
        for (int j = 0; j < 8; j++) af[j] = (short)f2bf(vals[j]);
        #pragma unroll
        for (int tp = 0; tp < 4; tp++) {
            const int t = ch * 4 + tp;
            short8 bo = *(const short8*)(Wop + ((long)(s * 16 + t) * 64 + lane) * 8);
            acc[tp] = __builtin_amdgcn_mfma_f32_16x16x32_bf16(af, bo, acc[tp], 0, 0, 0);
        }
    }

    #pragma unroll
    for (int tp = 0; tp < 4; tp++) {
        #pragma unroll
        for (int r = 0; r < 4; r++)
            out[(i0 + quad * 4 + r) * C_DIM + (ch * 4 + tp) * 16 + l15] = acc[tp][r];
    }
}

// ---------------------------------------------------------------------------
extern "C" void kernel_launch(void* const* d_in, const int* in_sizes, int n_in,
                              void* d_out, int out_size, void* d_ws, size_t ws_size,
                              hipStream_t stream)
{
    const float* query   = (const float*)d_in[0];
    const float* context = (const float*)d_in[1];
    const float* Wq      = (const float*)d_in[2];
    const float* Wk      = (const float*)d_in[3];
    const float* Wv      = (const float*)d_in[4];
    const float* Wo      = (const float*)d_in[5];
    float* out = (float*)d_out;

    char* ws = (char*)d_ws;
    unsigned short* Qb = (unsigned short*)(ws);                    // 2 MB [bh][n][32]
    unsigned short* Kb = (unsigned short*)(ws + (2 << 20));        // 2 MB [bh][n][32]
    unsigned short* Vb = (unsigned short*)(ws + (4 << 20));        // 2 MB [bh][32][n]
    unsigned short* AO = (unsigned short*)(ws + (6 << 20));        // 16 MB [8][b*n][128] bf16
    float*          Lb = (float*)(ws + (22 << 20));                // 1 MB [8][bh][n]
    unsigned short* Wp = (unsigned short*)(ws + (23 << 20));       // 256 KB packed

    wpack_kernel<<<dim3(64), dim3(256), 0, stream>>>(Wq, Wk, Wv, Wo, Wp);
    qkv_kernel<<<dim3(512), dim3(256), 0, stream>>>(query, context, Wp, Qb, Kb, Vb);
    attn_kernel<<<dim3(32 * BH * SPLITS), dim3(256), 0, stream>>>(
        Qb, Kb, Vb, AO, Lb);
    outproj_kernel<<<dim3(512), dim3(256), 0, stream>>>(AO, Lb, Wp, out);
}